// Round 1
// baseline (555.029 us; speedup 1.0000x reference)
//
#include <hip/hip_runtime.h>
#include <stdint.h>

#define S_LEN 2048
#define EMB   2048
#define NHEAD 32
#define HDIM  64
#define QKVN  3072   // 2048 q + 512 k + 512 v
#define KOFF  2048
#define VOFF  2560

typedef __attribute__((ext_vector_type(8))) short short8;
typedef __attribute__((ext_vector_type(4))) short short4v;
typedef __attribute__((ext_vector_type(4))) float f32x4;

__device__ __forceinline__ unsigned short f2bf(float f) {
  union { float f; unsigned u; } v; v.f = f;
  return (unsigned short)((v.u + 0x7fffu + ((v.u >> 16) & 1u)) >> 16);
}

__device__ __forceinline__ f32x4 mfma16(short8 a, short8 b, f32x4 c) {
  return __builtin_amdgcn_mfma_f32_16x16x32_bf16(a, b, c, 0, 0, 0);
}

__device__ __forceinline__ void gload_lds16(const void* g, void* l) {
  __builtin_amdgcn_global_load_lds(
      (const __attribute__((address_space(1))) void*)g,
      (__attribute__((address_space(3))) void*)l, 16, 0, 0);
}

// ---------------- fp32 -> bf16 convert (vectorized) ----------------
__global__ void k_cvt_bf16(const float* __restrict__ src,
                           unsigned short* __restrict__ dst, int n) {
  int i = (blockIdx.x * blockDim.x + threadIdx.x) * 4;
  int stride = gridDim.x * blockDim.x * 4;
  for (; i < n; i += stride) {
    float4 v = *reinterpret_cast<const float4*>(src + i);
    short4v o;
    o.x = (short)f2bf(v.x); o.y = (short)f2bf(v.y);
    o.z = (short)f2bf(v.z); o.w = (short)f2bf(v.w);
    *reinterpret_cast<short4v*>(dst + i) = o;
  }
}

__global__ void k_bias_cat(const float* __restrict__ bq, const float* __restrict__ bk,
                           const float* __restrict__ bv, float* __restrict__ dst) {
  int i = blockIdx.x * blockDim.x + threadIdx.x;   // grid covers exactly 3072
  if (i < 2048) dst[i] = bq[i];
  else if (i < 2560) dst[i] = bk[i - 2048];
  else dst[i] = bv[i - 2560];
}

// ---------------- GEMM: C[M,N] = A[M,K] @ B[N,K]^T + bias ----------------
// m97-style: 128x128 tile, BK=32, 4 waves (2x2), global_load_lds width 16.
template <typename OUT_T>
__global__ __launch_bounds__(256) void k_gemm_bt(
    const unsigned short* __restrict__ A, const unsigned short* __restrict__ B,
    const float* __restrict__ bias, OUT_T* __restrict__ C, int M, int N, int K) {
  __shared__ unsigned short As[128 * 32];
  __shared__ unsigned short Bs[128 * 32];
  const int t = threadIdx.x;
  const int l = t & 63;
  const int w = t >> 6;
  const int m0 = blockIdx.x * 128;
  const int n0 = blockIdx.y * 128;
  const int wm = w >> 1, wn = w & 1;

  f32x4 acc[4][4] = {};

  const unsigned short* ga0 = A + (size_t)(m0 + (t >> 2)) * K + (t & 3) * 8;
  const unsigned short* ga1 = ga0 + (size_t)64 * K;
  const unsigned short* gb0 = B + (size_t)(n0 + (t >> 2)) * K + (t & 3) * 8;
  const unsigned short* gb1 = gb0 + (size_t)64 * K;
  unsigned short* la0 = As + t * 8;          // byte offset t*16 (linear, matches lane x 16B)
  unsigned short* la1 = As + 2048 + t * 8;
  unsigned short* lb0 = Bs + t * 8;
  unsigned short* lb1 = Bs + 2048 + t * 8;

  const int lr = l & 15;
  const int lk = (l >> 4) * 8;
  const unsigned short* arow = As + (wm * 64 + lr) * 32 + lk;
  const unsigned short* brow = Bs + (wn * 64 + lr) * 32 + lk;

  for (int k0 = 0; k0 < K; k0 += 32) {
    gload_lds16(ga0, la0);
    gload_lds16(ga1, la1);
    gload_lds16(gb0, lb0);
    gload_lds16(gb1, lb1);
    ga0 += 32; ga1 += 32; gb0 += 32; gb1 += 32;
    __syncthreads();   // compiler emits vmcnt(0) before s_barrier -> LDS ready
    short8 af[4], bfv[4];
#pragma unroll
    for (int i = 0; i < 4; i++) {
      af[i]  = *reinterpret_cast<const short8*>(arow + i * 16 * 32);
      bfv[i] = *reinterpret_cast<const short8*>(brow + i * 16 * 32);
    }
#pragma unroll
    for (int i = 0; i < 4; i++)
#pragma unroll
      for (int j = 0; j < 4; j++)
        acc[i][j] = mfma16(af[i], bfv[j], acc[i][j]);
    __syncthreads();
  }

  const int lg = l >> 4;
#pragma unroll
  for (int i = 0; i < 4; i++) {
#pragma unroll
    for (int j = 0; j < 4; j++) {
      int col = n0 + wn * 64 + j * 16 + lr;
      float bb = bias[col];
#pragma unroll
      for (int r = 0; r < 4; r++) {
        int row = m0 + wm * 64 + i * 16 + lg * 4 + r;
        float val = acc[i][j][r] + bb;
        if constexpr (sizeof(OUT_T) == 2)
          C[(size_t)row * N + col] = (OUT_T)f2bf(val);
        else
          C[(size_t)row * N + col] = (OUT_T)val;
      }
    }
  }
}

// ---------------- V transpose: vT[gd][pos] = qkv[pos][VOFF+gd] ----------------
__global__ __launch_bounds__(256) void k_vT(const unsigned short* __restrict__ qkv,
                                            unsigned short* __restrict__ vT) {
  __shared__ unsigned short tile[64][72];
  const int t = threadIdx.x;
  const int p0 = (blockIdx.x & 31) * 64;
  const int g0 = (blockIdx.x >> 5) * 64;
  {
    const int pl = t >> 3;
    const int gl = (t & 7) * 8;
#pragma unroll
    for (int i = 0; i < 2; i++) {
      int p = pl + i * 32;
      short8 v = *reinterpret_cast<const short8*>(qkv + (size_t)(p0 + p) * QKVN + VOFF + g0 + gl);
#pragma unroll
      for (int j = 0; j < 8; j++) tile[p][gl + j] = (unsigned short)v[j];
    }
  }
  __syncthreads();
  {
    const int gr = t >> 3;
    const int pc = (t & 7) * 8;
#pragma unroll
    for (int i = 0; i < 2; i++) {
      int g = gr + i * 32;
      short8 o;
#pragma unroll
      for (int j = 0; j < 8; j++) o[j] = (short)tile[pc + j][g];
      *reinterpret_cast<short8*>(vT + (size_t)(g0 + g) * S_LEN + p0 + pc) = o;
    }
  }
}

// ---------------- fused attention: 1 block = 1 head x 16 q-rows ----------------
__global__ __launch_bounds__(512) void k_attn(
    const unsigned short* __restrict__ qkv, const unsigned short* __restrict__ vT,
    float* __restrict__ attn_w, unsigned short* __restrict__ hout) {
  __shared__ float sc[16 * 2052];   // pad 4 -> bank = (4*row + col)%32, 2-way max (free)
  __shared__ float red_mx[16];
  __shared__ float red_inv[16];
  __shared__ float pvred[8 * 64 * 4];

  const int t = threadIdx.x;
  const int l = t & 63;
  const int w = t >> 6;               // 8 waves
  const int h = blockIdx.x >> 7;      // head
  const int r0 = (blockIdx.x & 127) * 16;
  const int g = h >> 2;               // kv group
  const int lr = l & 15;
  const int lk = (l >> 4) * 8;

  // Q fragments (A operand): row = r0+lr, k = head-dim
  const unsigned short* qbase = qkv + (size_t)(r0 + lr) * QKVN + h * HDIM + lk;
  const short8 aq0 = *reinterpret_cast<const short8*>(qbase);
  const short8 aq1 = *reinterpret_cast<const short8*>(qbase + 32);

  // ---- scores: 128 n-tiles split across 8 waves ----
  const unsigned short* kbase = qkv + (size_t)KOFF + g * HDIM + lk;
  for (int nt = w; nt < 128; nt += 8) {
    const unsigned short* kp = kbase + (size_t)(nt * 16 + lr) * QKVN;
    short8 b0 = *reinterpret_cast<const short8*>(kp);
    short8 b1 = *reinterpret_cast<const short8*>(kp + 32);
    f32x4 a = {};
    a = mfma16(aq0, b0, a);
    a = mfma16(aq1, b1, a);
    const int colw = nt * 16 + lr;
#pragma unroll
    for (int r = 0; r < 4; r++)
      sc[((l >> 4) * 4 + r) * 2052 + colw] = a[r] * 0.125f;
  }
  __syncthreads();

  // ---- softmax reduce: each wave owns 2 rows, 32 lanes/row ----
  {
    const int row = 2 * w + (l >> 5);
    const int cj = l & 31;
    const float* srow = sc + row * 2052 + cj;
    float mx = -1e30f;
#pragma unroll 8
    for (int i = 0; i < 64; i++) mx = fmaxf(mx, srow[i * 32]);
#pragma unroll
    for (int m = 16; m >= 1; m >>= 1) mx = fmaxf(mx, __shfl_xor(mx, m, 64));
    float sm = 0.f;
#pragma unroll 8
    for (int i = 0; i < 64; i++) sm += __expf(srow[i * 32] - mx);
#pragma unroll
    for (int m = 16; m >= 1; m >>= 1) sm += __shfl_xor(sm, m, 64);
    if (cj == 0) { red_mx[row] = mx; red_inv[row] = 1.0f / sm; }
  }
  __syncthreads();

  // ---- normalize: write p back to LDS and to global attn_weights ----
  {
    float* aout = attn_w + (size_t)h * S_LEN * S_LEN + (size_t)r0 * S_LEN;
#pragma unroll 4
    for (int i = 0; i < 64; i++) {
      int rr = i >> 2, cc = ((i & 3) << 9) + t;
      float p = __expf(sc[rr * 2052 + cc] - red_mx[rr]) * red_inv[rr];
      sc[rr * 2052 + cc] = p;
      aout[(size_t)rr * S_LEN + cc] = p;
    }
  }
  __syncthreads();

  // ---- PV: wave (nt = w&3) handles dim-tile, kh = w>>2 splits K; dual acc ----
  {
    const int nt = w & 3;
    const int kh = w >> 2;
    const unsigned short* vtb = vT + (size_t)(g * HDIM + nt * 16 + lr) * S_LEN;
    const float* prow = sc + lr * 2052;
    f32x4 acc0 = {}, acc1 = {};
    for (int kb = kh * 1024; kb < kh * 1024 + 1024; kb += 64) {
      const float* sp = prow + kb + lk;
      f32x4 f0 = *reinterpret_cast<const f32x4*>(sp);
      f32x4 f1 = *reinterpret_cast<const f32x4*>(sp + 4);
      f32x4 f2 = *reinterpret_cast<const f32x4*>(sp + 32);
      f32x4 f3 = *reinterpret_cast<const f32x4*>(sp + 36);
      short8 a0, a1;
#pragma unroll
      for (int j = 0; j < 4; j++) { a0[j] = (short)f2bf(f0[j]); a0[j + 4] = (short)f2bf(f1[j]); }
#pragma unroll
      for (int j = 0; j < 4; j++) { a1[j] = (short)f2bf(f2[j]); a1[j + 4] = (short)f2bf(f3[j]); }
      short8 b0 = *reinterpret_cast<const short8*>(vtb + kb + lk);
      short8 b1 = *reinterpret_cast<const short8*>(vtb + kb + 32 + lk);
      acc0 = mfma16(a0, b0, acc0);
      acc1 = mfma16(a1, b1, acc1);
    }
    acc0 += acc1;
#pragma unroll
    for (int r = 0; r < 4; r++) pvred[(w * 64 + l) * 4 + r] = acc0[r];
  }
  __syncthreads();
  if (w < 4) {
    const int lg = l >> 4;
#pragma unroll
    for (int r = 0; r < 4; r++) {
      float v = pvred[(w * 64 + l) * 4 + r] + pvred[((w + 4) * 64 + l) * 4 + r];
      hout[(size_t)(r0 + lg * 4 + r) * EMB + h * HDIM + w * 16 + lr] = f2bf(v);
    }
  }
}

extern "C" void kernel_launch(void* const* d_in, const int* in_sizes, int n_in,
                              void* d_out, int out_size, void* d_ws, size_t ws_size,
                              hipStream_t stream) {
  const float* x  = (const float*)d_in[0];
  const float* Wq = (const float*)d_in[1];
  const float* bq = (const float*)d_in[2];
  const float* Wk = (const float*)d_in[3];
  const float* bk = (const float*)d_in[4];
  const float* Wv = (const float*)d_in[5];
  const float* bv = (const float*)d_in[6];
  const float* Wo = (const float*)d_in[7];
  const float* bo = (const float*)d_in[8];
  float* out = (float*)d_out;

  char* ws = (char*)d_ws;
  unsigned short* x_bf  = (unsigned short*)(ws);                 // 8 MiB
  unsigned short* wqkv  = (unsigned short*)(ws + (8ull  << 20)); // 12 MiB
  unsigned short* wo_bf = (unsigned short*)(ws + (20ull << 20)); // 8 MiB
  float*          bqkv  = (float*)         (ws + (28ull << 20)); // 12 KiB
  unsigned short* qkv   = (unsigned short*)(ws + (29ull << 20)); // 12 MiB
  unsigned short* vT    = (unsigned short*)(ws + (41ull << 20)); // 2 MiB
  unsigned short* hout  = (unsigned short*)(ws + (43ull << 20)); // 8 MiB

  k_cvt_bf16<<<1024, 256, 0, stream>>>(x,  x_bf, EMB * S_LEN);
  k_cvt_bf16<<<1024, 256, 0, stream>>>(Wq, wqkv, EMB * EMB);
  k_cvt_bf16<<<512,  256, 0, stream>>>(Wk, wqkv + 2048 * 2048, 512 * 2048);
  k_cvt_bf16<<<512,  256, 0, stream>>>(Wv, wqkv + 2560 * 2048, 512 * 2048);
  k_cvt_bf16<<<1024, 256, 0, stream>>>(Wo, wo_bf, EMB * EMB);
  k_bias_cat<<<12, 256, 0, stream>>>(bq, bk, bv, bqkv);

  dim3 g1(16, 24);  // M/128 x N/128
  k_gemm_bt<unsigned short><<<g1, 256, 0, stream>>>(x_bf, wqkv, bqkv, qkv, 2048, 3072, 2048);
  k_vT<<<256, 256, 0, stream>>>(qkv, vT);
  k_attn<<<4096, 512, 0, stream>>>(qkv, vT, out, hout);
  dim3 g2(16, 16);
  k_gemm_bt<float><<<g2, 256, 0, stream>>>(hout, wo_bf, bo, out + (size_t)NHEAD * S_LEN * S_LEN, 2048, 2048, 2048);
}

// Round 2
// 432.129 us; speedup vs baseline: 1.2844x; 1.2844x over previous
//
#include <hip/hip_runtime.h>
#include <stdint.h>

#define S_LEN 2048
#define EMB   2048
#define NHEAD 32
#define HDIM  64
#define QKVN  3072   // 2048 q + 512 k + 512 v
#define KOFF  2048
#define VOFF  2560

typedef __attribute__((ext_vector_type(8))) short short8;
typedef __attribute__((ext_vector_type(4))) short short4v;
typedef __attribute__((ext_vector_type(4))) float f32x4;

__device__ __forceinline__ unsigned short f2bf(float f) {
  union { float f; unsigned u; } v; v.f = f;
  return (unsigned short)((v.u + 0x7fffu + ((v.u >> 16) & 1u)) >> 16);
}

__device__ __forceinline__ f32x4 mfma16(short8 a, short8 b, f32x4 c) {
  return __builtin_amdgcn_mfma_f32_16x16x32_bf16(a, b, c, 0, 0, 0);
}

__device__ __forceinline__ void gload_lds16(const void* g, void* l) {
  __builtin_amdgcn_global_load_lds(
      (const __attribute__((address_space(1))) void*)g,
      (__attribute__((address_space(3))) void*)l, 16, 0, 0);
}

// ---------------- fp32 -> bf16 convert (vectorized) ----------------
__global__ void k_cvt_bf16(const float* __restrict__ src,
                           unsigned short* __restrict__ dst, int n) {
  int i = (blockIdx.x * blockDim.x + threadIdx.x) * 4;
  int stride = gridDim.x * blockDim.x * 4;
  for (; i < n; i += stride) {
    float4 v = *reinterpret_cast<const float4*>(src + i);
    short4v o;
    o.x = (short)f2bf(v.x); o.y = (short)f2bf(v.y);
    o.z = (short)f2bf(v.z); o.w = (short)f2bf(v.w);
    *reinterpret_cast<short4v*>(dst + i) = o;
  }
}

__global__ void k_bias_cat(const float* __restrict__ bq, const float* __restrict__ bk,
                           const float* __restrict__ bv, float* __restrict__ dst) {
  int i = blockIdx.x * blockDim.x + threadIdx.x;   // grid covers exactly 3072
  if (i < 2048) dst[i] = bq[i];
  else if (i < 2560) dst[i] = bk[i - 2048];
  else dst[i] = bv[i - 2560];
}

// ---------------- GEMM: C[M,N] = A[M,K] @ B[N,K]^T + bias ----------------
template <typename OUT_T>
__global__ __launch_bounds__(256) void k_gemm_bt(
    const unsigned short* __restrict__ A, const unsigned short* __restrict__ B,
    const float* __restrict__ bias, OUT_T* __restrict__ C, int M, int N, int K) {
  __shared__ unsigned short As[128 * 32];
  __shared__ unsigned short Bs[128 * 32];
  const int t = threadIdx.x;
  const int l = t & 63;
  const int w = t >> 6;
  const int m0 = blockIdx.x * 128;
  const int n0 = blockIdx.y * 128;
  const int wm = w >> 1, wn = w & 1;

  f32x4 acc[4][4] = {};

  const unsigned short* ga0 = A + (size_t)(m0 + (t >> 2)) * K + (t & 3) * 8;
  const unsigned short* ga1 = ga0 + (size_t)64 * K;
  const unsigned short* gb0 = B + (size_t)(n0 + (t >> 2)) * K + (t & 3) * 8;
  const unsigned short* gb1 = gb0 + (size_t)64 * K;
  unsigned short* la0 = As + t * 8;
  unsigned short* la1 = As + 2048 + t * 8;
  unsigned short* lb0 = Bs + t * 8;
  unsigned short* lb1 = Bs + 2048 + t * 8;

  const int lr = l & 15;
  const int lk = (l >> 4) * 8;
  const unsigned short* arow = As + (wm * 64 + lr) * 32 + lk;
  const unsigned short* brow = Bs + (wn * 64 + lr) * 32 + lk;

  for (int k0 = 0; k0 < K; k0 += 32) {
    gload_lds16(ga0, la0);
    gload_lds16(ga1, la1);
    gload_lds16(gb0, lb0);
    gload_lds16(gb1, lb1);
    ga0 += 32; ga1 += 32; gb0 += 32; gb1 += 32;
    __syncthreads();
    short8 af[4], bfv[4];
#pragma unroll
    for (int i = 0; i < 4; i++) {
      af[i]  = *reinterpret_cast<const short8*>(arow + i * 16 * 32);
      bfv[i] = *reinterpret_cast<const short8*>(brow + i * 16 * 32);
    }
#pragma unroll
    for (int i = 0; i < 4; i++)
#pragma unroll
      for (int j = 0; j < 4; j++)
        acc[i][j] = mfma16(af[i], bfv[j], acc[i][j]);
    __syncthreads();
  }

  const int lg = l >> 4;
#pragma unroll
  for (int i = 0; i < 4; i++) {
#pragma unroll
    for (int j = 0; j < 4; j++) {
      int col = n0 + wn * 64 + j * 16 + lr;
      float bb = bias[col];
#pragma unroll
      for (int r = 0; r < 4; r++) {
        int row = m0 + wm * 64 + i * 16 + lg * 4 + r;
        float val = acc[i][j][r] + bb;
        if constexpr (sizeof(OUT_T) == 2)
          C[(size_t)row * N + col] = (OUT_T)f2bf(val);
        else
          C[(size_t)row * N + col] = (OUT_T)val;
      }
    }
  }
}

// ---------------- V transpose: vT[gd][pos] = qkv[pos][VOFF+gd] ----------------
__global__ __launch_bounds__(256) void k_vT(const unsigned short* __restrict__ qkv,
                                            unsigned short* __restrict__ vT) {
  __shared__ unsigned short tile[64][72];
  const int t = threadIdx.x;
  const int p0 = (blockIdx.x & 31) * 64;
  const int g0 = (blockIdx.x >> 5) * 64;
  {
    const int pl = t >> 3;
    const int gl = (t & 7) * 8;
#pragma unroll
    for (int i = 0; i < 2; i++) {
      int p = pl + i * 32;
      short8 v = *reinterpret_cast<const short8*>(qkv + (size_t)(p0 + p) * QKVN + VOFF + g0 + gl);
#pragma unroll
      for (int j = 0; j < 8; j++) tile[p][gl + j] = (unsigned short)v[j];
    }
  }
  __syncthreads();
  {
    const int gr = t >> 3;
    const int pc = (t & 7) * 8;
#pragma unroll
    for (int i = 0; i < 2; i++) {
      int g = gr + i * 32;
      short8 o;
#pragma unroll
      for (int j = 0; j < 8; j++) o[j] = (short)tile[pc + j][g];
      *reinterpret_cast<short8*>(vT + (size_t)(g0 + g) * S_LEN + p0 + pc) = o;
    }
  }
}

// ---------------- fused attention v2: scores in registers (swapped QK^T) ----
// Block = 1 head x 16 q-rows, 512 threads (8 waves). Wave w owns cols
// [w*256, (w+1)*256). Swapped mfma(K,Q): lane owns q-row (l&15), 64 score
// values in chunks of 4 consecutive cols. Softmax in-register, one exp pass.
// p -> global f32x4 nontemporal; p -> LDS bf16 XOR-swizzled for PV.
__global__ __launch_bounds__(512, 4) void k_attn(
    const unsigned short* __restrict__ qkv, const unsigned short* __restrict__ vT,
    float* __restrict__ attn_w, unsigned short* __restrict__ hout) {
  __shared__ unsigned short p_lds[16 * 2048];   // 64 KB, byte ^ ((row&7)<<4)
  __shared__ float red_mx[8 * 16];
  __shared__ float red_sm[8 * 16];
  __shared__ float pvred[8 * 64 * 4];           // 8 KB

  const int t = threadIdx.x;
  const int l = t & 63;
  const int w = t >> 6;               // 8 waves
  const int h = blockIdx.x >> 7;      // head
  const int r0 = (blockIdx.x & 127) * 16;
  const int g = h >> 2;               // kv group
  const int lr = l & 15;
  const int lg = l >> 4;              // 0..3
  const int lk = lg * 8;

  // Q fragment = B operand: col/q-row r0+lr, k = lk..lk+7 (+32 for 2nd half)
  const unsigned short* qbase = qkv + (size_t)(r0 + lr) * QKVN + h * HDIM + lk;
  const short8 bq0 = *reinterpret_cast<const short8*>(qbase);
  const short8 bq1 = *reinterpret_cast<const short8*>(qbase + 32);

  // ---- scores^T in regs: acc[i] covers cols (w*16+i)*16 + lg*4 + {0..3} ----
  f32x4 acc[16];
  const unsigned short* kbase = qkv + (size_t)KOFF + g * HDIM + lk;
#pragma unroll
  for (int i = 0; i < 16; i++) {
    const unsigned short* kp = kbase + (size_t)((w * 16 + i) * 16 + lr) * QKVN;
    short8 a0 = *reinterpret_cast<const short8*>(kp);
    short8 a1 = *reinterpret_cast<const short8*>(kp + 32);
    f32x4 a = {};
    a = mfma16(a0, bq0, a);
    a = mfma16(a1, bq1, a);
    acc[i] = a * 0.125f;
  }

  // ---- row max: every value in this lane belongs to q-row r0+lr ----
  float mx = -1e30f;
#pragma unroll
  for (int i = 0; i < 16; i++) {
    mx = fmaxf(mx, fmaxf(fmaxf(acc[i][0], acc[i][1]), fmaxf(acc[i][2], acc[i][3])));
  }
  mx = fmaxf(mx, __shfl_xor(mx, 16, 64));
  mx = fmaxf(mx, __shfl_xor(mx, 32, 64));
  if (l < 16) red_mx[w * 16 + l] = mx;
  __syncthreads();
  float bm = red_mx[lr];
#pragma unroll
  for (int j = 1; j < 8; j++) bm = fmaxf(bm, red_mx[j * 16 + lr]);

  // ---- single exp pass + row sum ----
  float sm = 0.f;
#pragma unroll
  for (int i = 0; i < 16; i++) {
#pragma unroll
    for (int r = 0; r < 4; r++) {
      float e = __expf(acc[i][r] - bm);
      acc[i][r] = e;
      sm += e;
    }
  }
  sm += __shfl_xor(sm, 16, 64);
  sm += __shfl_xor(sm, 32, 64);
  if (l < 16) red_sm[w * 16 + l] = sm;
  __syncthreads();
  float bs = 0.f;
#pragma unroll
  for (int j = 0; j < 8; j++) bs += red_sm[j * 16 + lr];
  const float inv = 1.0f / bs;

  // ---- normalize; write attn f32x4 (nontemporal) + p_lds bf16 (swizzled) ----
  float* aout = attn_w + (size_t)h * S_LEN * S_LEN + (size_t)(r0 + lr) * S_LEN;
  const unsigned swz = (unsigned)((lr & 7) << 4);
  const unsigned rowb = (unsigned)(lr * 4096);
#pragma unroll
  for (int i = 0; i < 16; i++) {
    f32x4 p = acc[i] * inv;
    const int col = (w * 16 + i) * 16 + lg * 4;
    __builtin_nontemporal_store(p, reinterpret_cast<f32x4*>(aout + col));
    short4v pb;
    pb.x = (short)f2bf(p[0]); pb.y = (short)f2bf(p[1]);
    pb.z = (short)f2bf(p[2]); pb.w = (short)f2bf(p[3]);
    unsigned byte = (rowb + (unsigned)(col * 2)) ^ swz;
    *reinterpret_cast<short4v*>(reinterpret_cast<char*>(p_lds) + byte) = pb;
  }
  __syncthreads();

  // ---- PV: wave (w&3)=hd-tile, (w>>2)=K half; A from p_lds, B from vT ----
  {
    const int hd0 = (w & 3) * 16;
    const int kh = w >> 2;
    const unsigned short* vtb = vT + (size_t)(g * HDIM + hd0 + lr) * S_LEN;
    f32x4 pv0 = {}, pv1 = {};
    const char* pbase = reinterpret_cast<const char*>(p_lds);
    for (int kb = kh * 1024; kb < kh * 1024 + 1024; kb += 64) {
      const unsigned b0 = (rowb + (unsigned)((kb + lk) * 2)) ^ swz;
      const unsigned b1 = (rowb + (unsigned)((kb + lk + 32) * 2)) ^ swz;
      short8 a0 = *reinterpret_cast<const short8*>(pbase + b0);
      short8 a1 = *reinterpret_cast<const short8*>(pbase + b1);
      short8 v0 = *reinterpret_cast<const short8*>(vtb + kb + lk);
      short8 v1 = *reinterpret_cast<const short8*>(vtb + kb + 32 + lk);
      pv0 = mfma16(a0, v0, pv0);
      pv1 = mfma16(a1, v1, pv1);
    }
    pv0 += pv1;
#pragma unroll
    for (int r = 0; r < 4; r++) pvred[(w * 64 + l) * 4 + r] = pv0[r];
  }
  __syncthreads();
  if (w < 4) {
#pragma unroll
    for (int r = 0; r < 4; r++) {
      float v = pvred[(w * 64 + l) * 4 + r] + pvred[((w + 4) * 64 + l) * 4 + r];
      hout[(size_t)(r0 + lg * 4 + r) * EMB + h * HDIM + w * 16 + lr] = f2bf(v);
    }
  }
}

extern "C" void kernel_launch(void* const* d_in, const int* in_sizes, int n_in,
                              void* d_out, int out_size, void* d_ws, size_t ws_size,
                              hipStream_t stream) {
  const float* x  = (const float*)d_in[0];
  const float* Wq = (const float*)d_in[1];
  const float* bq = (const float*)d_in[2];
  const float* Wk = (const float*)d_in[3];
  const float* bk = (const float*)d_in[4];
  const float* Wv = (const float*)d_in[5];
  const float* bv = (const float*)d_in[6];
  const float* Wo = (const float*)d_in[7];
  const float* bo = (const float*)d_in[8];
  float* out = (float*)d_out;

  char* ws = (char*)d_ws;
  unsigned short* x_bf  = (unsigned short*)(ws);                 // 8 MiB
  unsigned short* wqkv  = (unsigned short*)(ws + (8ull  << 20)); // 12 MiB
  unsigned short* wo_bf = (unsigned short*)(ws + (20ull << 20)); // 8 MiB
  float*          bqkv  = (float*)         (ws + (28ull << 20)); // 12 KiB
  unsigned short* qkv   = (unsigned short*)(ws + (29ull << 20)); // 12 MiB
  unsigned short* vT    = (unsigned short*)(ws + (41ull << 20)); // 2 MiB
  unsigned short* hout  = (unsigned short*)(ws + (43ull << 20)); // 8 MiB

  k_cvt_bf16<<<1024, 256, 0, stream>>>(x,  x_bf, EMB * S_LEN);
  k_cvt_bf16<<<1024, 256, 0, stream>>>(Wq, wqkv, EMB * EMB);
  k_cvt_bf16<<<512,  256, 0, stream>>>(Wk, wqkv + 2048 * 2048, 512 * 2048);
  k_cvt_bf16<<<512,  256, 0, stream>>>(Wv, wqkv + 2560 * 2048, 512 * 2048);
  k_cvt_bf16<<<1024, 256, 0, stream>>>(Wo, wo_bf, EMB * EMB);
  k_bias_cat<<<12, 256, 0, stream>>>(bq, bk, bv, bqkv);

  dim3 g1(16, 24);  // M/128 x N/128
  k_gemm_bt<unsigned short><<<g1, 256, 0, stream>>>(x_bf, wqkv, bqkv, qkv, 2048, 3072, 2048);
  k_vT<<<256, 256, 0, stream>>>(qkv, vT);
  k_attn<<<4096, 512, 0, stream>>>(qkv, vT, out, hout);
  dim3 g2(16, 16);
  k_gemm_bt<float><<<g2, 256, 0, stream>>>(hout, wo_bf, bo, out + (size_t)NHEAD * S_LEN * S_LEN, 2048, 2048, 2048);
}